// Round 2
// baseline (150.825 us; speedup 1.0000x reference)
//
#include <hip/hip_runtime.h>

typedef __bf16 bf16x4 __attribute__((ext_vector_type(4)));
typedef __bf16 bf16x8 __attribute__((ext_vector_type(8)));
typedef float f32x4 __attribute__((ext_vector_type(4)));

__device__ __forceinline__ f32x4 mfma16(bf16x8 a, bf16x8 b, f32x4 c) {
    return __builtin_amdgcn_mfma_f32_16x16x32_bf16(a, b, c, 0, 0, 0);
}

// Fused 3-layer MLP: out = (relu(relu(x@W0^T + b0)@W1^T + b1))@W2^T + b2
// x: [N,64] f32, W0:[64,64], W1:[64,64], W2:[32,64], out: [N,32] f32.
// Swapped-operand MFMA (D = W·X^T tiles): lane (lr,lg) holds H[m=lr][n=16t+4lg+r],
// giving contiguous-column epilogues: b64 LDS staging writes, dwordx4 output stores,
// and bias folded into the accumulator init (f32x4 broadcast read from LDS).
__global__ __launch_bounds__(256, 4) void cheb_mlp_kernel(
    const float* __restrict__ x,
    const float* __restrict__ W0, const float* __restrict__ b0v,
    const float* __restrict__ W1, const float* __restrict__ b1v,
    const float* __restrict__ W2, const float* __restrict__ b2v,
    float* __restrict__ out, int n_nodes)
{
    __shared__ __bf16 w0s[64][72];
    __shared__ __bf16 w1s[64][72];
    __shared__ __bf16 w2s[32][72];
    __shared__ float bias0[64];
    __shared__ float bias1[64];
    __shared__ float bias2[32];
    __shared__ __bf16 hbuf[4][16][72];   // per-wave activation staging (72: 16B-aligned rows)

    const int tid = threadIdx.x;

    // One-time weight convert fp32 -> bf16 into LDS.
    for (int i = tid; i < 64 * 64; i += 256) {
        int r = i >> 6, c = i & 63;
        w0s[r][c] = (__bf16)W0[i];
        w1s[r][c] = (__bf16)W1[i];
    }
    for (int i = tid; i < 32 * 64; i += 256) {
        int r = i >> 6, c = i & 63;
        w2s[r][c] = (__bf16)W2[i];
    }
    if (tid < 64) { bias0[tid] = b0v[tid]; bias1[tid] = b1v[tid]; }
    if (tid >= 64 && tid < 96) bias2[tid - 64] = b2v[tid - 64];
    __syncthreads();

    const int wave = tid >> 6;
    const int lane = tid & 63;
    const int lr = lane & 15;   // matrix row (A) / col (B,D) within 16-tile
    const int lg = lane >> 4;   // quarter-wave: k-offset 8*lg; D-row 4*lg + r

    // Hoist W0/W1 fragments into registers (A-operand layout: W[16t+lr][32s+8lg+j]).
    bf16x8 fw0[4][2], fw1[4][2], fw2[2][2];
#pragma unroll
    for (int t = 0; t < 4; ++t)
#pragma unroll
        for (int s = 0; s < 2; ++s) {
            fw0[t][s] = *(const bf16x8*)&w0s[t * 16 + lr][s * 32 + lg * 8];
            fw1[t][s] = *(const bf16x8*)&w1s[t * 16 + lr][s * 32 + lg * 8];
        }
#pragma unroll
    for (int t = 0; t < 2; ++t)
#pragma unroll
        for (int s = 0; s < 2; ++s)
            fw2[t][s] = *(const bf16x8*)&w2s[t * 16 + lr][s * 32 + lg * 8];

    const int wave_base = blockIdx.x * 256 + wave * 64;

    f32x4 cx0, cx1, cx2, cx3;
    const float* xbase = x + (size_t)lr * 64 + lg * 8;
    if (wave_base < n_nodes) {
        const float* xp = xbase + (size_t)wave_base * 64;
        cx0 = *(const f32x4*)(xp);
        cx1 = *(const f32x4*)(xp + 4);
        cx2 = *(const f32x4*)(xp + 32);
        cx3 = *(const f32x4*)(xp + 36);
    }

#pragma unroll
    for (int mt = 0; mt < 4; ++mt) {
        const int m_cur = wave_base + mt * 16;
        if (m_cur >= n_nodes) break;

        // 1-deep prefetch of next M-tile.
        f32x4 nx0, nx1, nx2, nx3;
        const bool has_next = (mt < 3) && (m_cur + 16 < n_nodes);
        if (has_next) {
            const float* xp = xbase + (size_t)(m_cur + 16) * 64;
            nx0 = *(const f32x4*)(xp);
            nx1 = *(const f32x4*)(xp + 4);
            nx2 = *(const f32x4*)(xp + 32);
            nx3 = *(const f32x4*)(xp + 36);
        }

        // X fragment (B-operand layout: X[lr][32s+8lg+j]), fp32 -> bf16.
        bf16x8 ax0, ax1;
#pragma unroll
        for (int j = 0; j < 4; ++j) {
            ax0[j]     = (__bf16)cx0[j];
            ax0[j + 4] = (__bf16)cx1[j];
            ax1[j]     = (__bf16)cx2[j];
            ax1[j + 4] = (__bf16)cx3[j];
        }

        // ---- layer 0: acc init = bias (broadcast vec read), D = W0 · X^T ----
        f32x4 acc[4];
#pragma unroll
        for (int t = 0; t < 4; ++t) {
            acc[t] = *(const f32x4*)&bias0[t * 16 + lg * 4];
            acc[t] = mfma16(fw0[t][0], ax0, acc[t]);
            acc[t] = mfma16(fw0[t][1], ax1, acc[t]);
        }
        // relu + pack 4 consecutive cols -> one b64 LDS write per t.
#pragma unroll
        for (int t = 0; t < 4; ++t) {
            bf16x4 pk;
#pragma unroll
            for (int r = 0; r < 4; ++r) {
                float v = acc[t][r];
                pk[r] = (__bf16)(v > 0.f ? v : 0.f);
            }
            *(bf16x4*)&hbuf[wave][lr][t * 16 + lg * 4] = pk;
        }

        // ---- layer 1 ----
        bf16x8 ah0 = *(const bf16x8*)&hbuf[wave][lr][lg * 8];
        bf16x8 ah1 = *(const bf16x8*)&hbuf[wave][lr][32 + lg * 8];
#pragma unroll
        for (int t = 0; t < 4; ++t) {
            acc[t] = *(const f32x4*)&bias1[t * 16 + lg * 4];
            acc[t] = mfma16(fw1[t][0], ah0, acc[t]);
            acc[t] = mfma16(fw1[t][1], ah1, acc[t]);
        }
#pragma unroll
        for (int t = 0; t < 4; ++t) {
            bf16x4 pk;
#pragma unroll
            for (int r = 0; r < 4; ++r) {
                float v = acc[t][r];
                pk[r] = (__bf16)(v > 0.f ? v : 0.f);
            }
            *(bf16x4*)&hbuf[wave][lr][t * 16 + lg * 4] = pk;
        }

        // ---- layer 2 (no relu): two dwordx4 stores per lane ----
        bf16x8 ag0 = *(const bf16x8*)&hbuf[wave][lr][lg * 8];
        bf16x8 ag1 = *(const bf16x8*)&hbuf[wave][lr][32 + lg * 8];
#pragma unroll
        for (int t = 0; t < 2; ++t) {
            f32x4 a2 = *(const f32x4*)&bias2[t * 16 + lg * 4];
            a2 = mfma16(fw2[t][0], ag0, a2);
            a2 = mfma16(fw2[t][1], ag1, a2);
            *(f32x4*)&out[(size_t)(m_cur + lr) * 32 + t * 16 + lg * 4] = a2;
        }

        if (has_next) { cx0 = nx0; cx1 = nx1; cx2 = nx2; cx3 = nx3; }
    }
}

extern "C" void kernel_launch(void* const* d_in, const int* in_sizes, int n_in,
                              void* d_out, int out_size, void* d_ws, size_t ws_size,
                              hipStream_t stream) {
    const float* x  = (const float*)d_in[0];
    // d_in[1] = edge_index (int64), d_in[2] = edge_weight — dead inputs for K=1 ChebConv.
    const float* W0 = (const float*)d_in[3];
    const float* b0 = (const float*)d_in[4];
    const float* W1 = (const float*)d_in[5];
    const float* b1 = (const float*)d_in[6];
    const float* W2 = (const float*)d_in[7];
    const float* b2 = (const float*)d_in[8];
    float* out = (float*)d_out;

    const int n_nodes = in_sizes[0] / 64;           // 1,000,000
    const int grid = (n_nodes + 255) / 256;         // 256 nodes per block
    cheb_mlp_kernel<<<grid, 256, 0, stream>>>(x, W0, b0, W1, b1, W2, b2, out, n_nodes);
}

// Round 3
// 82.963 us; speedup vs baseline: 1.8180x; 1.8180x over previous
//
#include <hip/hip_runtime.h>

typedef __bf16 bf16x4 __attribute__((ext_vector_type(4)));
typedef __bf16 bf16x8 __attribute__((ext_vector_type(8)));
typedef float f32x4 __attribute__((ext_vector_type(4)));

__device__ __forceinline__ f32x4 mfma16(bf16x8 a, bf16x8 b, f32x4 c) {
    return __builtin_amdgcn_mfma_f32_16x16x32_bf16(a, b, c, 0, 0, 0);
}

// Fused 3-layer MLP: out = relu(relu(x@W0^T+b0)@W1^T+b1)@W2^T + b2
// x:[N,64] f32 -> out:[N,32] f32. bf16 MFMA, fp32 accum.
// Swapped-operand MFMA (D = W·X^T): lane (lr,lg) holds H[ch=16t+4lg+r][node=lr],
// contiguous-channel epilogues (b64 LDS staging, dwordx4 stores, bias-in-acc-init).
// 2-deep x prefetch (two named register slots) to keep >=8KB/wave in flight.
__global__ __launch_bounds__(256) void cheb_mlp_kernel(
    const float* __restrict__ x,
    const float* __restrict__ W0, const float* __restrict__ b0v,
    const float* __restrict__ W1, const float* __restrict__ b1v,
    const float* __restrict__ W2, const float* __restrict__ b2v,
    float* __restrict__ out, int n_nodes)
{
    __shared__ __bf16 w0s[64][72];
    __shared__ __bf16 w1s[64][72];
    __shared__ __bf16 w2s[32][72];
    __shared__ float bias0[64], bias1[64], bias2[32];
    __shared__ __bf16 hbuf[4][16][72];   // per-wave activation staging

    const int tid = threadIdx.x;

    for (int i = tid; i < 64 * 64; i += 256) {
        int r = i >> 6, c = i & 63;
        w0s[r][c] = (__bf16)W0[i];
        w1s[r][c] = (__bf16)W1[i];
    }
    for (int i = tid; i < 32 * 64; i += 256) {
        w2s[i >> 6][i & 63] = (__bf16)W2[i];
    }
    if (tid < 64)      { bias0[tid] = b0v[tid]; bias1[tid] = b1v[tid]; }
    else if (tid < 96) { bias2[tid - 64] = b2v[tid - 64]; }
    __syncthreads();

    const int wave = tid >> 6;
    const int lane = tid & 63;
    const int lr = lane & 15;   // A-row (W channel) / D-col (node)
    const int lg = lane >> 4;   // k-offset 8*lg; D-row 4*lg + r

    // Hoist all weight fragments (A-operand layout: W[16t+lr][32s+8lg+j]). 80 VGPR.
    bf16x8 fw0[4][2], fw1[4][2], fw2[2][2];
#pragma unroll
    for (int t = 0; t < 4; ++t)
#pragma unroll
        for (int s = 0; s < 2; ++s) {
            fw0[t][s] = *(const bf16x8*)&w0s[t * 16 + lr][s * 32 + lg * 8];
            fw1[t][s] = *(const bf16x8*)&w1s[t * 16 + lr][s * 32 + lg * 8];
        }
#pragma unroll
    for (int t = 0; t < 2; ++t)
#pragma unroll
        for (int s = 0; s < 2; ++s)
            fw2[t][s] = *(const bf16x8*)&w2s[t * 16 + lr][s * 32 + lg * 8];

    const int wave_base = blockIdx.x * 256 + wave * 64;
    if (wave_base >= n_nodes) return;            // no barriers after this point
    const int nt = min(4, (n_nodes - wave_base) >> 4);   // N%16==0: no partial tiles

    const float* xbase = x + (size_t)(wave_base + lr) * 64 + lg * 8;

#define LDX(mt, s0, s1, s2, s3)                                    \
    {                                                              \
        const float* xp = xbase + (size_t)(mt) * 1024;             \
        s0 = *(const f32x4*)(xp);                                  \
        s1 = *(const f32x4*)(xp + 4);                              \
        s2 = *(const f32x4*)(xp + 32);                             \
        s3 = *(const f32x4*)(xp + 36);                             \
    }

    // X fragment build (B-operand layout: X[node=lr][32s+8lg+j]), fp32->bf16.
#define CVT(c0, c1, c2, c3, ax0, ax1)                              \
    {                                                              \
        _Pragma("unroll")                                          \
        for (int j = 0; j < 4; ++j) {                              \
            ax0[j]     = (__bf16)c0[j];                            \
            ax0[j + 4] = (__bf16)c1[j];                            \
            ax1[j]     = (__bf16)c2[j];                            \
            ax1[j + 4] = (__bf16)c3[j];                            \
        }                                                          \
    }

    auto layers = [&](bf16x8 ax0, bf16x8 ax1, int m_cur) {
        // ---- layer 0 ----
        f32x4 acc[4];
#pragma unroll
        for (int t = 0; t < 4; ++t) {
            acc[t] = *(const f32x4*)&bias0[t * 16 + lg * 4];
            acc[t] = mfma16(fw0[t][0], ax0, acc[t]);
            acc[t] = mfma16(fw0[t][1], ax1, acc[t]);
        }
#pragma unroll
        for (int t = 0; t < 4; ++t) {
            bf16x4 pk;
#pragma unroll
            for (int r = 0; r < 4; ++r) {
                float v = acc[t][r];
                pk[r] = (__bf16)(v > 0.f ? v : 0.f);
            }
            *(bf16x4*)&hbuf[wave][lr][t * 16 + lg * 4] = pk;
        }
        // ---- layer 1 ----
        bf16x8 ah0 = *(const bf16x8*)&hbuf[wave][lr][lg * 8];
        bf16x8 ah1 = *(const bf16x8*)&hbuf[wave][lr][32 + lg * 8];
#pragma unroll
        for (int t = 0; t < 4; ++t) {
            acc[t] = *(const f32x4*)&bias1[t * 16 + lg * 4];
            acc[t] = mfma16(fw1[t][0], ah0, acc[t]);
            acc[t] = mfma16(fw1[t][1], ah1, acc[t]);
        }
#pragma unroll
        for (int t = 0; t < 4; ++t) {
            bf16x4 pk;
#pragma unroll
            for (int r = 0; r < 4; ++r) {
                float v = acc[t][r];
                pk[r] = (__bf16)(v > 0.f ? v : 0.f);
            }
            *(bf16x4*)&hbuf[wave][lr][t * 16 + lg * 4] = pk;
        }
        // ---- layer 2 (no relu): two dwordx4 stores ----
        bf16x8 ag0 = *(const bf16x8*)&hbuf[wave][lr][lg * 8];
        bf16x8 ag1 = *(const bf16x8*)&hbuf[wave][lr][32 + lg * 8];
#pragma unroll
        for (int t = 0; t < 2; ++t) {
            f32x4 a2 = *(const f32x4*)&bias2[t * 16 + lg * 4];
            a2 = mfma16(fw2[t][0], ag0, a2);
            a2 = mfma16(fw2[t][1], ag1, a2);
            *(f32x4*)&out[(size_t)(m_cur + lr) * 32 + t * 16 + lg * 4] = a2;
        }
    };

    // 2-deep prefetch over up to 4 tiles, two named slots (all indices static).
    f32x4 pa0, pa1, pa2, pa3, pb0, pb1, pb2, pb3;
    LDX(0, pa0, pa1, pa2, pa3);
    if (nt > 1) LDX(1, pb0, pb1, pb2, pb3);

    {   // tile 0: consume A, then refill A with tile 2
        bf16x8 ax0, ax1;
        CVT(pa0, pa1, pa2, pa3, ax0, ax1);
        if (nt > 2) LDX(2, pa0, pa1, pa2, pa3);
        layers(ax0, ax1, wave_base);
    }
    if (nt > 1) {   // tile 1: consume B, refill B with tile 3
        bf16x8 ax0, ax1;
        CVT(pb0, pb1, pb2, pb3, ax0, ax1);
        if (nt > 3) LDX(3, pb0, pb1, pb2, pb3);
        layers(ax0, ax1, wave_base + 16);
    }
    if (nt > 2) {   // tile 2: consume A
        bf16x8 ax0, ax1;
        CVT(pa0, pa1, pa2, pa3, ax0, ax1);
        layers(ax0, ax1, wave_base + 32);
    }
    if (nt > 3) {   // tile 3: consume B
        bf16x8 ax0, ax1;
        CVT(pb0, pb1, pb2, pb3, ax0, ax1);
        layers(ax0, ax1, wave_base + 48);
    }
#undef LDX
#undef CVT
}

extern "C" void kernel_launch(void* const* d_in, const int* in_sizes, int n_in,
                              void* d_out, int out_size, void* d_ws, size_t ws_size,
                              hipStream_t stream) {
    const float* x  = (const float*)d_in[0];
    // d_in[1] = edge_index (int64), d_in[2] = edge_weight — dead inputs (ChebConv K=1).
    const float* W0 = (const float*)d_in[3];
    const float* b0 = (const float*)d_in[4];
    const float* W1 = (const float*)d_in[5];
    const float* b1 = (const float*)d_in[6];
    const float* W2 = (const float*)d_in[7];
    const float* b2 = (const float*)d_in[8];
    float* out = (float*)d_out;

    const int n_nodes = in_sizes[0] / 64;           // 1,000,000
    const int grid = (n_nodes + 255) / 256;         // 256 nodes / block
    cheb_mlp_kernel<<<grid, 256, 0, stream>>>(x, W0, b0, W1, b1, W2, b2, out, n_nodes);
}

// Round 4
// 69.527 us; speedup vs baseline: 2.1693x; 1.1932x over previous
//
#include <hip/hip_runtime.h>

typedef __bf16 bf16x4 __attribute__((ext_vector_type(4)));
typedef __bf16 bf16x8 __attribute__((ext_vector_type(8)));
typedef float f32x4 __attribute__((ext_vector_type(4)));

__device__ __forceinline__ f32x4 mfma16(bf16x8 a, bf16x8 b, f32x4 c) {
    return __builtin_amdgcn_mfma_f32_16x16x32_bf16(a, b, c, 0, 0, 0);
}

// Fused 3-layer MLP: out = relu(relu(x@W0^T+b0)@W1^T+b1)@W2^T + b2
// x:[N,64] f32 -> out:[N,32] f32. bf16 MFMA, fp32 accum.
// Swapped-operand MFMA (D = W·X^T): lane (lr,lg) holds H[ch=16t+4lg+r][node=lr].
// VGPR budget play: only fw0/fw2 hoisted (48 regs); fw1 streamed from LDS per
// tile; 1-deep x prefetch. Target <=128 VGPR => 4 waves/SIMD (16 waves/CU).
__global__ __launch_bounds__(256) void cheb_mlp_kernel(
    const float* __restrict__ x,
    const float* __restrict__ W0, const float* __restrict__ b0v,
    const float* __restrict__ W1, const float* __restrict__ b1v,
    const float* __restrict__ W2, const float* __restrict__ b2v,
    float* __restrict__ out, int n_nodes)
{
    __shared__ __bf16 w0s[64][72];
    __shared__ __bf16 w1s[64][72];
    __shared__ __bf16 w2s[32][72];
    __shared__ float bias0[64], bias1[64], bias2[32];
    __shared__ __bf16 hbuf[4][16][72];   // per-wave activation staging

    const int tid = threadIdx.x;

    for (int i = tid; i < 64 * 64; i += 256) {
        int r = i >> 6, c = i & 63;
        w0s[r][c] = (__bf16)W0[i];
        w1s[r][c] = (__bf16)W1[i];
    }
    for (int i = tid; i < 32 * 64; i += 256) {
        w2s[i >> 6][i & 63] = (__bf16)W2[i];
    }
    if (tid < 64)      { bias0[tid] = b0v[tid]; bias1[tid] = b1v[tid]; }
    else if (tid < 96) { bias2[tid - 64] = b2v[tid - 64]; }
    __syncthreads();

    const int wave = tid >> 6;
    const int lane = tid & 63;
    const int lr = lane & 15;   // A-row (W channel) / D-col (node)
    const int lg = lane >> 4;   // k-offset 8*lg; D-row 4*lg + r

    // Hoist fw0 + fw2 only (A-operand layout: W[16t+lr][32s+8lg+j]) = 48 VGPR.
    bf16x8 fw0[4][2], fw2[2][2];
#pragma unroll
    for (int t = 0; t < 4; ++t)
#pragma unroll
        for (int s = 0; s < 2; ++s)
            fw0[t][s] = *(const bf16x8*)&w0s[t * 16 + lr][s * 32 + lg * 8];
#pragma unroll
    for (int t = 0; t < 2; ++t)
#pragma unroll
        for (int s = 0; s < 2; ++s)
            fw2[t][s] = *(const bf16x8*)&w2s[t * 16 + lr][s * 32 + lg * 8];

    const int wave_base = blockIdx.x * 256 + wave * 64;
    if (wave_base >= n_nodes) return;            // no barriers after this point
    const int rem = (n_nodes - wave_base) >> 4;  // N%16==0: whole tiles only
    const int nt = rem < 4 ? rem : 4;

    const float* xbase = x + (size_t)(wave_base + lr) * 64 + lg * 8;

    f32x4 cx0, cx1, cx2, cx3;
    {
        const float* xp = xbase;
        cx0 = *(const f32x4*)(xp);
        cx1 = *(const f32x4*)(xp + 4);
        cx2 = *(const f32x4*)(xp + 32);
        cx3 = *(const f32x4*)(xp + 36);
    }

#pragma unroll
    for (int mt = 0; mt < 4; ++mt) {
        if (mt >= nt) break;
        const int m_cur = wave_base + mt * 16;

        // 1-deep prefetch of next tile.
        f32x4 nx0, nx1, nx2, nx3;
        const bool has_next = (mt + 1 < nt);
        if (has_next) {
            const float* xp = xbase + (size_t)(mt + 1) * 1024;
            nx0 = *(const f32x4*)(xp);
            nx1 = *(const f32x4*)(xp + 4);
            nx2 = *(const f32x4*)(xp + 32);
            nx3 = *(const f32x4*)(xp + 36);
        }

        // X fragment (B-operand layout: X[node=lr][32s+8lg+j]), fp32->bf16.
        bf16x8 ax0, ax1;
#pragma unroll
        for (int j = 0; j < 4; ++j) {
            ax0[j]     = (__bf16)cx0[j];
            ax0[j + 4] = (__bf16)cx1[j];
            ax1[j]     = (__bf16)cx2[j];
            ax1[j + 4] = (__bf16)cx3[j];
        }

        // ---- layer 0 (fw0 from registers) ----
        f32x4 acc[4];
#pragma unroll
        for (int t = 0; t < 4; ++t) {
            acc[t] = *(const f32x4*)&bias0[t * 16 + lg * 4];
            acc[t] = mfma16(fw0[t][0], ax0, acc[t]);
            acc[t] = mfma16(fw0[t][1], ax1, acc[t]);
        }
#pragma unroll
        for (int t = 0; t < 4; ++t) {
            bf16x4 pk;
#pragma unroll
            for (int r = 0; r < 4; ++r) {
                float v = acc[t][r];
                pk[r] = (__bf16)(v > 0.f ? v : 0.f);
            }
            *(bf16x4*)&hbuf[wave][lr][t * 16 + lg * 4] = pk;
        }

        // ---- layer 1 (fw1 streamed from LDS, <=2-way bank aliasing = free) ----
        bf16x8 ah0 = *(const bf16x8*)&hbuf[wave][lr][lg * 8];
        bf16x8 ah1 = *(const bf16x8*)&hbuf[wave][lr][32 + lg * 8];
#pragma unroll
        for (int t = 0; t < 4; ++t) {
            bf16x8 f0 = *(const bf16x8*)&w1s[t * 16 + lr][lg * 8];
            bf16x8 f1 = *(const bf16x8*)&w1s[t * 16 + lr][32 + lg * 8];
            acc[t] = *(const f32x4*)&bias1[t * 16 + lg * 4];
            acc[t] = mfma16(f0, ah0, acc[t]);
            acc[t] = mfma16(f1, ah1, acc[t]);
        }
#pragma unroll
        for (int t = 0; t < 4; ++t) {
            bf16x4 pk;
#pragma unroll
            for (int r = 0; r < 4; ++r) {
                float v = acc[t][r];
                pk[r] = (__bf16)(v > 0.f ? v : 0.f);
            }
            *(bf16x4*)&hbuf[wave][lr][t * 16 + lg * 4] = pk;
        }

        // ---- layer 2 (fw2 from registers, no relu): nontemporal dwordx4 stores ----
        bf16x8 ag0 = *(const bf16x8*)&hbuf[wave][lr][lg * 8];
        bf16x8 ag1 = *(const bf16x8*)&hbuf[wave][lr][32 + lg * 8];
#pragma unroll
        for (int t = 0; t < 2; ++t) {
            f32x4 a2 = *(const f32x4*)&bias2[t * 16 + lg * 4];
            a2 = mfma16(fw2[t][0], ag0, a2);
            a2 = mfma16(fw2[t][1], ag1, a2);
            __builtin_nontemporal_store(a2, (f32x4*)&out[(size_t)(m_cur + lr) * 32 + t * 16 + lg * 4]);
        }

        if (has_next) { cx0 = nx0; cx1 = nx1; cx2 = nx2; cx3 = nx3; }
    }
}

extern "C" void kernel_launch(void* const* d_in, const int* in_sizes, int n_in,
                              void* d_out, int out_size, void* d_ws, size_t ws_size,
                              hipStream_t stream) {
    const float* x  = (const float*)d_in[0];
    // d_in[1] = edge_index (int64), d_in[2] = edge_weight — dead inputs (ChebConv K=1).
    const float* W0 = (const float*)d_in[3];
    const float* b0 = (const float*)d_in[4];
    const float* W1 = (const float*)d_in[5];
    const float* b1 = (const float*)d_in[6];
    const float* W2 = (const float*)d_in[7];
    const float* b2 = (const float*)d_in[8];
    float* out = (float*)d_out;

    const int n_nodes = in_sizes[0] / 64;           // 1,000,000
    const int grid = (n_nodes + 255) / 256;         // 256 nodes / block
    cheb_mlp_kernel<<<grid, 256, 0, stream>>>(x, W0, b0, W1, b1, W2, b2, out, n_nodes);
}